// Round 1
// baseline (799.524 us; speedup 1.0000x reference)
//
#include <hip/hip_runtime.h>
#include <math.h>

#define NEG_SLOPE 0.2f
#define LN_EPS 1e-5f

__device__ __forceinline__ float lrelu(float v){ return v > 0.f ? v : NEG_SLOPE * v; }
__device__ __forceinline__ float eluf (float v){ return v > 0.f ? v : expm1f(v); }

// ---------------- CSR build ----------------

__global__ void k_deg(const int* __restrict__ dst, int* __restrict__ deg, int E){
    int e = blockIdx.x * 256 + threadIdx.x;
    if (e < E) atomicAdd(&deg[dst[e]], 1);
}

__global__ void k_chunk_sum(const int* __restrict__ deg, int* __restrict__ partial, int N){
    __shared__ int lds[256];
    int t = threadIdx.x;
    int v = blockIdx.x * 256 + t;
    lds[t] = (v < N) ? deg[v] : 0;
    __syncthreads();
    for (int s = 128; s > 0; s >>= 1){
        if (t < s) lds[t] += lds[t + s];
        __syncthreads();
    }
    if (t == 0) partial[blockIdx.x] = lds[0];
}

// single block, 512 threads, exclusive scan of partial[0..n), n <= 512
__global__ void k_scan_partial(int* __restrict__ partial, int n){
    __shared__ int lds[512];
    int t = threadIdx.x;
    int x = (t < n) ? partial[t] : 0;
    lds[t] = x;
    __syncthreads();
    for (int s = 1; s < 512; s <<= 1){
        int a = (t >= s) ? lds[t - s] : 0;
        __syncthreads();
        lds[t] += a;
        __syncthreads();
    }
    if (t < n) partial[t] = lds[t] - x;   // exclusive
}

__global__ void k_scan_final(const int* __restrict__ deg, const int* __restrict__ partial,
                             int* __restrict__ row_ptr, int* __restrict__ cursor, int N){
    __shared__ int lds[256];
    int t = threadIdx.x;
    int v = blockIdx.x * 256 + t;
    int x = (v < N) ? deg[v] : 0;
    lds[t] = x;
    __syncthreads();
    for (int s = 1; s < 256; s <<= 1){
        int a = (t >= s) ? lds[t - s] : 0;
        __syncthreads();
        lds[t] += a;
        __syncthreads();
    }
    int rp = partial[blockIdx.x] + lds[t] - x;  // exclusive prefix
    if (v < N){
        row_ptr[v] = rp;
        cursor[v]  = rp;          // cursor may alias deg: deg[v] already read above
        if (v == N - 1) row_ptr[N] = rp + x;
    }
}

__global__ void k_fill(const int* __restrict__ src, const int* __restrict__ dst,
                       int* __restrict__ cursor, int* __restrict__ col, int E){
    int e = blockIdx.x * 256 + threadIdx.x;
    if (e < E){
        int d = dst[e];
        int pos = atomicAdd(&cursor[d], 1);
        col[pos] = src[e];
    }
}

// ---------------- GAT layer 1 linear: x[N,3] @ W1[3,128], e_src/e_dst ----------------
// one wave per node; lane handles channels c and c+64

__global__ __launch_bounds__(256) void k_lin1(
    const float* __restrict__ x, const float* __restrict__ W1,
    const float* __restrict__ asrc, const float* __restrict__ adst,
    float* __restrict__ hlin, float* __restrict__ es, float* __restrict__ ed, int N)
{
    __shared__ float sW[384], sA[128], sB[128];
    int t = threadIdx.x;
    for (int i = t; i < 384; i += 256) sW[i] = W1[i];
    for (int i = t; i < 128; i += 256){ sA[i] = asrc[i]; sB[i] = adst[i]; }
    __syncthreads();
    int lane = t & 63;
    int v = blockIdx.x * 4 + (t >> 6);
    if (v >= N) return;
    float x0 = x[(size_t)v*3], x1 = x[(size_t)v*3+1], x2 = x[(size_t)v*3+2];
    int c0 = lane, c1 = lane + 64;
    float h0 = x0*sW[c0] + x1*sW[128+c0] + x2*sW[256+c0];
    float h1 = x0*sW[c1] + x1*sW[128+c1] + x2*sW[256+c1];
    hlin[(size_t)v*128 + c0] = h0;
    hlin[(size_t)v*128 + c1] = h1;
    // a_src flat index: (c>>5)*32 + (c&31) == c
    float ts0 = h0*sA[c0], ts1 = h1*sA[c1];
    float td0 = h0*sB[c0], td1 = h1*sB[c1];
    #pragma unroll
    for (int m = 16; m >= 1; m >>= 1){
        ts0 += __shfl_xor(ts0, m); ts1 += __shfl_xor(ts1, m);
        td0 += __shfl_xor(td0, m); td1 += __shfl_xor(td1, m);
    }
    if ((lane & 31) == 0){
        int h = lane >> 5;                // 0 or 1
        es[(size_t)v*4 + h    ] = ts0;    // head h   (channels 0..63)
        es[(size_t)v*4 + h + 2] = ts1;    // head h+2 (channels 64..127)
        ed[(size_t)v*4 + h    ] = td0;
        ed[(size_t)v*4 + h + 2] = td1;
    }
}

// ---------------- GAT layer 1 attention + aggregation + bias + ELU + LN ----------------

__global__ __launch_bounds__(256) void k_agg1(
    const float* __restrict__ hlin, const float* __restrict__ es, const float* __restrict__ ed,
    const int* __restrict__ row_ptr, const int* __restrict__ col,
    const float* __restrict__ b1, const float* __restrict__ g1, const float* __restrict__ be1,
    float* __restrict__ h1, int N)
{
    int t = threadIdx.x; int lane = t & 63;
    int v = blockIdx.x * 4 + (t >> 6);
    if (v >= N) return;
    float4 edv = *(const float4*)(ed + (size_t)v*4);
    float4 esv = *(const float4*)(es + (size_t)v*4);
    float e0 = lrelu(esv.x+edv.x), e1 = lrelu(esv.y+edv.y);
    float e2 = lrelu(esv.z+edv.z), e3 = lrelu(esv.w+edv.w);
    float m0=e0, m1=e1, m2=e2, m3=e3;
    int beg = row_ptr[v], end = row_ptr[v+1];
    for (int j = beg + lane; j < end; j += 64){
        int s = col[j];
        float4 q = *(const float4*)(es + (size_t)s*4);
        m0 = fmaxf(m0, lrelu(q.x+edv.x));
        m1 = fmaxf(m1, lrelu(q.y+edv.y));
        m2 = fmaxf(m2, lrelu(q.z+edv.z));
        m3 = fmaxf(m3, lrelu(q.w+edv.w));
    }
    #pragma unroll
    for (int k = 32; k >= 1; k >>= 1){
        m0 = fmaxf(m0, __shfl_xor(m0,k)); m1 = fmaxf(m1, __shfl_xor(m1,k));
        m2 = fmaxf(m2, __shfl_xor(m2,k)); m3 = fmaxf(m3, __shfl_xor(m3,k));
    }
    float s0=0.f, s1=0.f, s2=0.f, s3=0.f;
    for (int j = beg + lane; j < end; j += 64){
        int s = col[j];
        float4 q = *(const float4*)(es + (size_t)s*4);
        s0 += __expf(lrelu(q.x+edv.x) - m0);
        s1 += __expf(lrelu(q.y+edv.y) - m1);
        s2 += __expf(lrelu(q.z+edv.z) - m2);
        s3 += __expf(lrelu(q.w+edv.w) - m3);
    }
    #pragma unroll
    for (int k = 32; k >= 1; k >>= 1){
        s0 += __shfl_xor(s0,k); s1 += __shfl_xor(s1,k);
        s2 += __shfl_xor(s2,k); s3 += __shfl_xor(s3,k);
    }
    s0 += __expf(e0-m0); s1 += __expf(e1-m1); s2 += __expf(e2-m2); s3 += __expf(e3-m3);
    float i0 = 1.f/(s0+1e-16f), i1 = 1.f/(s1+1e-16f);
    float i2 = 1.f/(s2+1e-16f), i3 = 1.f/(s3+1e-16f);
    bool lo = lane < 32;
    int c0 = lane, c1 = lane + 64;
    float mA = lo?m0:m1, mB = lo?m2:m3;
    float iA = lo?i0:i1, iB = lo?i2:i3;
    float eA = lo?e0:e1, eB = lo?e2:e3;
    float dA = lo?edv.x:edv.y, dB = lo?edv.z:edv.w;
    float accA = __expf(eA-mA) * hlin[(size_t)v*128 + c0];   // self-loop
    float accB = __expf(eB-mB) * hlin[(size_t)v*128 + c1];
    for (int j = beg; j < end; ++j){
        int s = col[j];
        float4 q = *(const float4*)(es + (size_t)s*4);
        float pA = __expf(lrelu((lo?q.x:q.y) + dA) - mA);
        float pB = __expf(lrelu((lo?q.z:q.w) + dB) - mB);
        const float* hs = hlin + (size_t)s*128;
        accA += pA * hs[c0];
        accB += pB * hs[c1];
    }
    accA *= iA; accB *= iB;
    float oA = eluf(accA + b1[c0]);
    float oB = eluf(accB + b1[c1]);
    // LayerNorm over 128 channels (2 per lane)
    float su = oA + oB;
    #pragma unroll
    for (int k = 32; k >= 1; k >>= 1) su += __shfl_xor(su, k);
    float mean = su * (1.f/128.f);
    float aA = oA - mean, aB = oB - mean;
    float vs = aA*aA + aB*aB;
    #pragma unroll
    for (int k = 32; k >= 1; k >>= 1) vs += __shfl_xor(vs, k);
    float rstd = rsqrtf(vs * (1.f/128.f) + LN_EPS);
    h1[(size_t)v*128 + c0] = aA*rstd*g1[c0] + be1[c0];
    h1[(size_t)v*128 + c1] = aB*rstd*g1[c1] + be1[c1];
}

// ---------------- GAT layer 2 linear: h1[N,128] @ W2[128,64] ----------------

__global__ __launch_bounds__(256) void k_lin2(
    const float* __restrict__ h1, const float* __restrict__ W2,
    const float* __restrict__ asrc, const float* __restrict__ adst,
    float* __restrict__ hlin2, float* __restrict__ es2, float* __restrict__ ed2, int N)
{
    __shared__ float sW[128*64];
    __shared__ float sA[64], sB[64];
    int t = threadIdx.x;
    for (int i = t; i < 128*64; i += 256) sW[i] = W2[i];
    if (t < 64){ sA[t] = asrc[t]; sB[t] = adst[t]; }
    __syncthreads();
    int lane = t & 63;
    int v = blockIdx.x * 4 + (t >> 6);
    if (v >= N) return;
    const float* hv = h1 + (size_t)v*128;
    float acc = 0.f;
    #pragma unroll 8
    for (int k = 0; k < 128; k += 4){
        float4 h4 = *(const float4*)(hv + k);
        acc += h4.x * sW[(k  )*64 + lane];
        acc += h4.y * sW[(k+1)*64 + lane];
        acc += h4.z * sW[(k+2)*64 + lane];
        acc += h4.w * sW[(k+3)*64 + lane];
    }
    hlin2[(size_t)v*64 + lane] = acc;
    float ts = acc * sA[lane], td = acc * sB[lane];
    #pragma unroll
    for (int m = 16; m >= 1; m >>= 1){
        ts += __shfl_xor(ts, m); td += __shfl_xor(td, m);
    }
    if ((lane & 31) == 0){
        int h = lane >> 5;
        es2[(size_t)v*2 + h] = ts;
        ed2[(size_t)v*2 + h] = td;
    }
}

// ---------------- GAT layer 2 attn+agg + head-mean + b2 + ELU + skip + LN ----------------

__global__ __launch_bounds__(256) void k_agg2(
    const float* __restrict__ hlin2, const float* __restrict__ es2, const float* __restrict__ ed2,
    const int* __restrict__ row_ptr, const int* __restrict__ col,
    const float* __restrict__ x, const float* __restrict__ Wskip, const float* __restrict__ bskip,
    const float* __restrict__ b2, const float* __restrict__ g2, const float* __restrict__ be2,
    float* __restrict__ h2, int N)
{
    int t = threadIdx.x; int lane = t & 63;
    int v = blockIdx.x * 4 + (t >> 6);
    if (v >= N) return;
    float2 edv = *(const float2*)(ed2 + (size_t)v*2);
    float2 esv = *(const float2*)(es2 + (size_t)v*2);
    float e0 = lrelu(esv.x+edv.x), e1 = lrelu(esv.y+edv.y);
    float m0 = e0, m1 = e1;
    int beg = row_ptr[v], end = row_ptr[v+1];
    for (int j = beg + lane; j < end; j += 64){
        int s = col[j];
        float2 q = *(const float2*)(es2 + (size_t)s*2);
        m0 = fmaxf(m0, lrelu(q.x+edv.x));
        m1 = fmaxf(m1, lrelu(q.y+edv.y));
    }
    #pragma unroll
    for (int k = 32; k >= 1; k >>= 1){
        m0 = fmaxf(m0, __shfl_xor(m0,k)); m1 = fmaxf(m1, __shfl_xor(m1,k));
    }
    float s0 = 0.f, s1 = 0.f;
    for (int j = beg + lane; j < end; j += 64){
        int s = col[j];
        float2 q = *(const float2*)(es2 + (size_t)s*2);
        s0 += __expf(lrelu(q.x+edv.x) - m0);
        s1 += __expf(lrelu(q.y+edv.y) - m1);
    }
    #pragma unroll
    for (int k = 32; k >= 1; k >>= 1){ s0 += __shfl_xor(s0,k); s1 += __shfl_xor(s1,k); }
    s0 += __expf(e0-m0); s1 += __expf(e1-m1);
    float i0 = 1.f/(s0+1e-16f), i1 = 1.f/(s1+1e-16f);
    bool lo = lane < 32;
    float mC = lo?m0:m1, iC = lo?i0:i1, dC = lo?edv.x:edv.y, eC = lo?e0:e1;
    float acc = __expf(eC-mC) * hlin2[(size_t)v*64 + lane];   // self-loop
    for (int j = beg; j < end; ++j){
        int s = col[j];
        float2 q = *(const float2*)(es2 + (size_t)s*2);
        float p = __expf(lrelu((lo?q.x:q.y) + dC) - mC);
        acc += p * hlin2[(size_t)s*64 + lane];
    }
    acc *= iC;
    float other = __shfl(acc, (lane + 32) & 63);
    if (lane < 32){
        float o = 0.5f * (acc + other) + b2[lane];   // mean over 2 heads + bias
        o = eluf(o);
        float sk = x[(size_t)v*3]*Wskip[lane] + x[(size_t)v*3+1]*Wskip[32+lane]
                 + x[(size_t)v*3+2]*Wskip[64+lane] + bskip[lane];
        float z = o + sk;
        float su = z;
        #pragma unroll
        for (int k = 16; k >= 1; k >>= 1) su += __shfl_xor(su, k);
        float mean = su * (1.f/32.f);
        float d = z - mean;
        float vs = d*d;
        #pragma unroll
        for (int k = 16; k >= 1; k >>= 1) vs += __shfl_xor(vs, k);
        float rstd = rsqrtf(vs * (1.f/32.f) + LN_EPS);
        h2[(size_t)v*32 + lane] = d*rstd*g2[lane] + be2[lane];
    }
}

// ---------------- pooling: per-graph mean/max/std (batch sorted) + projection ----------------

__global__ __launch_bounds__(256) void k_pool(
    const float* __restrict__ h2, const int* __restrict__ batch,
    const float* __restrict__ Wp, const float* __restrict__ bp,
    float* __restrict__ out, int N)
{
    int g = blockIdx.x; int t = threadIdx.x;
    __shared__ int sBeg, sEnd;
    if (t == 0){
        int lo = 0, hi = N;
        while (lo < hi){ int mid = (lo+hi) >> 1; if (batch[mid] < g) lo = mid+1; else hi = mid; }
        sBeg = lo;
        lo = sBeg; hi = N;
        while (lo < hi){ int mid = (lo+hi) >> 1; if (batch[mid] < g+1) lo = mid+1; else hi = mid; }
        sEnd = lo;
    }
    __syncthreads();
    int beg = sBeg, end = sEnd;
    int ch = t & 31, grp = t >> 5;   // 8 groups of 32 channels
    float sum = 0.f, sq = 0.f, mx = -INFINITY;
    for (int i = beg + grp; i < end; i += 8){
        float val = h2[(size_t)i*32 + ch];
        sum += val; sq += val*val; mx = fmaxf(mx, val);
    }
    __shared__ float lsum[256], lsq[256], lmx[256];
    lsum[t] = sum; lsq[t] = sq; lmx[t] = mx;
    __syncthreads();
    for (int s = 4; s >= 1; s >>= 1){
        if (grp < s){
            lsum[t] += lsum[t + s*32];
            lsq [t] += lsq [t + s*32];
            lmx [t]  = fmaxf(lmx[t], lmx[t + s*32]);
        }
        __syncthreads();
    }
    __shared__ float feat[96];
    if (t < 32){
        float cnt = fmaxf((float)(end - beg), 1.f);
        float mean = lsum[t] / cnt;
        float var  = lsq[t] / cnt - mean*mean;
        feat[t]      = mean;
        feat[32 + t] = lmx[t];
        feat[64 + t] = sqrtf(fmaxf(var, 0.f));
    }
    __syncthreads();
    if (t < 48){
        float acc = bp[t];
        #pragma unroll 8
        for (int k = 0; k < 96; ++k) acc += feat[k] * Wp[k*48 + t];
        out[(size_t)g*48 + t] = acc;
    }
}

// ---------------- launcher ----------------

extern "C" void kernel_launch(void* const* d_in, const int* in_sizes, int n_in,
                              void* d_out, int out_size, void* d_ws, size_t ws_size,
                              hipStream_t stream)
{
    const float* x     = (const float*)d_in[0];
    const int*   ei    = (const int*)  d_in[1];
    const int*   batch = (const int*)  d_in[2];
    const float* W1    = (const float*)d_in[3];
    const float* as1   = (const float*)d_in[4];
    const float* ad1   = (const float*)d_in[5];
    const float* b1    = (const float*)d_in[6];
    const float* W2    = (const float*)d_in[7];
    const float* as2   = (const float*)d_in[8];
    const float* ad2   = (const float*)d_in[9];
    const float* b2    = (const float*)d_in[10];
    const float* Wskip = (const float*)d_in[11];
    const float* bskip = (const float*)d_in[12];
    const float* g1    = (const float*)d_in[13];
    const float* be1   = (const float*)d_in[14];
    const float* g2    = (const float*)d_in[15];
    const float* be2   = (const float*)d_in[16];
    const float* Wp    = (const float*)d_in[17];
    const float* bp    = (const float*)d_in[18];

    int N = in_sizes[0] / 3;
    int E = in_sizes[1] / 2;
    int B = out_size / 48;
    const int* src = ei;
    const int* dst = ei + E;

    char* w = (char*)d_ws;
    auto alloc = [&](size_t bytes) -> char* {
        char* p = w; w += (bytes + 255) & ~(size_t)255; return p;
    };
    int*   row_ptr = (int*)  alloc((size_t)(N+1)*4);
    int*   deg     = (int*)  alloc((size_t)N*4);       // reused as fill cursor
    int*   partial = (int*)  alloc(4*1024);
    int*   col     = (int*)  alloc((size_t)E*4);
    float* hlin    = (float*)alloc((size_t)N*128*4);   // layer2 reuses first N*64
    float* es      = (float*)alloc((size_t)N*4*4);     // layer2 reuses first N*2
    float* ed      = (float*)alloc((size_t)N*4*4);
    float* h1      = (float*)alloc((size_t)N*128*4);
    float* h2      = (float*)alloc((size_t)N*32*4);
    (void)ws_size;

    hipMemsetAsync(deg, 0, (size_t)N*4, stream);

    int eb  = (E + 255) / 256;
    int nch = (N + 255) / 256;            // 391 <= 512: single-block scan ok
    int nb  = (N + 3) / 4;

    k_deg        <<<eb, 256, 0, stream>>>(dst, deg, E);
    k_chunk_sum  <<<nch, 256, 0, stream>>>(deg, partial, N);
    k_scan_partial<<<1, 512, 0, stream>>>(partial, nch);
    k_scan_final <<<nch, 256, 0, stream>>>(deg, partial, row_ptr, deg, N);
    k_fill       <<<eb, 256, 0, stream>>>(src, dst, deg, col, E);

    k_lin1 <<<nb, 256, 0, stream>>>(x, W1, as1, ad1, hlin, es, ed, N);
    k_agg1 <<<nb, 256, 0, stream>>>(hlin, es, ed, row_ptr, col, b1, g1, be1, h1, N);
    k_lin2 <<<nb, 256, 0, stream>>>(h1, W2, as2, ad2, hlin, es, ed, N);
    k_agg2 <<<nb, 256, 0, stream>>>(hlin, es, ed, row_ptr, col, x, Wskip, bskip,
                                    b2, g2, be2, h2, N);
    k_pool <<<B, 256, 0, stream>>>(h2, batch, Wp, bp, (float*)d_out, N);
}

// Round 2
// 605.483 us; speedup vs baseline: 1.3205x; 1.3205x over previous
//
#include <hip/hip_runtime.h>
#include <math.h>

#define NEG_SLOPE 0.2f
#define LN_EPS 1e-5f

__device__ __forceinline__ float lrelu(float v){ return v > 0.f ? v : NEG_SLOPE * v; }
__device__ __forceinline__ float eluf (float v){ return v > 0.f ? v : expm1f(v); }

__device__ __forceinline__ unsigned short f2bf(float f){
    unsigned x = __float_as_uint(f);
    unsigned r = (x + 0x7fffu + ((x >> 16) & 1u)) >> 16;   // round-nearest-even
    return (unsigned short)r;
}
__device__ __forceinline__ float bf_lo(unsigned u){ return __uint_as_float(u << 16); }
__device__ __forceinline__ float bf_hi(unsigned u){ return __uint_as_float(u & 0xffff0000u); }

// ---------------- CSR build ----------------

__global__ void k_deg(const int* __restrict__ dst, int* __restrict__ deg, int E){
    int e = blockIdx.x * 256 + threadIdx.x;
    if (e < E) atomicAdd(&deg[dst[e]], 1);
}

__global__ void k_chunk_sum(const int* __restrict__ deg, int* __restrict__ partial, int N){
    __shared__ int lds[256];
    int t = threadIdx.x;
    int v = blockIdx.x * 256 + t;
    lds[t] = (v < N) ? deg[v] : 0;
    __syncthreads();
    for (int s = 128; s > 0; s >>= 1){
        if (t < s) lds[t] += lds[t + s];
        __syncthreads();
    }
    if (t == 0) partial[blockIdx.x] = lds[0];
}

__global__ void k_scan_partial(int* __restrict__ partial, int n){
    __shared__ int lds[512];
    int t = threadIdx.x;
    int x = (t < n) ? partial[t] : 0;
    lds[t] = x;
    __syncthreads();
    for (int s = 1; s < 512; s <<= 1){
        int a = (t >= s) ? lds[t - s] : 0;
        __syncthreads();
        lds[t] += a;
        __syncthreads();
    }
    if (t < n) partial[t] = lds[t] - x;   // exclusive
}

__global__ void k_scan_final(const int* __restrict__ deg, const int* __restrict__ partial,
                             int* __restrict__ row_ptr, int* __restrict__ cursor, int N){
    __shared__ int lds[256];
    int t = threadIdx.x;
    int v = blockIdx.x * 256 + t;
    int x = (v < N) ? deg[v] : 0;
    lds[t] = x;
    __syncthreads();
    for (int s = 1; s < 256; s <<= 1){
        int a = (t >= s) ? lds[t - s] : 0;
        __syncthreads();
        lds[t] += a;
        __syncthreads();
    }
    int rp = partial[blockIdx.x] + lds[t] - x;  // exclusive prefix
    if (v < N){
        row_ptr[v] = rp;
        cursor[v]  = rp;
        if (v == N - 1) row_ptr[N] = rp + x;
    }
}

__global__ void k_fill(const int* __restrict__ src, const int* __restrict__ dst,
                       int* __restrict__ cursor, int* __restrict__ col, int E){
    int e = blockIdx.x * 256 + threadIdx.x;
    if (e < E){
        int d = dst[e];
        int pos = atomicAdd(&cursor[d], 1);
        col[pos] = src[e];
    }
}

// ---------------- layer 1 linear: x[N,3] @ W1[3,128] -> bf16, e_src/e_dst ----------------
// one wave per node; lane handles channels 2*lane, 2*lane+1 (head = lane>>4)

__global__ __launch_bounds__(256) void k_lin1(
    const float* __restrict__ x, const float* __restrict__ W1,
    const float* __restrict__ asrc, const float* __restrict__ adst,
    unsigned* __restrict__ hlinb, float* __restrict__ es, float* __restrict__ ed, int N)
{
    __shared__ float sW[384], sA[128], sB[128];
    int t = threadIdx.x;
    for (int i = t; i < 384; i += 256) sW[i] = W1[i];
    for (int i = t; i < 128; i += 256){ sA[i] = asrc[i]; sB[i] = adst[i]; }
    __syncthreads();
    int lane = t & 63;
    int v = blockIdx.x * 4 + (t >> 6);
    if (v >= N) return;
    float x0 = x[(size_t)v*3], x1 = x[(size_t)v*3+1], x2 = x[(size_t)v*3+2];
    int c = lane * 2;
    float h0 = x0*sW[c  ] + x1*sW[128+c  ] + x2*sW[256+c  ];
    float h1 = x0*sW[c+1] + x1*sW[128+c+1] + x2*sW[256+c+1];
    hlinb[(size_t)v*64 + lane] = (unsigned)f2bf(h0) | ((unsigned)f2bf(h1) << 16);
    int hsel = lane >> 4;
    float ts = h0*sA[c] + h1*sA[c+1];
    float td = h0*sB[c] + h1*sB[c+1];
    #pragma unroll
    for (int m = 8; m >= 1; m >>= 1){
        ts += __shfl_xor(ts, m); td += __shfl_xor(td, m);
    }
    if ((lane & 15) == 0){
        es[(size_t)v*4 + hsel] = ts;
        ed[(size_t)v*4 + hsel] = td;
    }
}

// ---------------- layer 1: fused single-pass attention + agg + bias + ELU + LN ----------------

__global__ __launch_bounds__(256) void k_agg1(
    const unsigned* __restrict__ hlinb,     // [N][64] bf16x2
    const float* __restrict__ es, const float* __restrict__ ed,
    const int* __restrict__ row_ptr, const int* __restrict__ col,
    const float* __restrict__ b1, const float* __restrict__ g1, const float* __restrict__ be1,
    float* __restrict__ h1, int N)
{
    __shared__ float sp[4][4][68];   // [wave][head][edge], padded (banks jj+4h)
    int t = threadIdx.x, lane = t & 63, w = t >> 6;
    int v = blockIdx.x * 4 + w;
    if (v >= N) return;
    float4 edv = *(const float4*)(ed + (size_t)v*4);
    float4 esv = *(const float4*)(es + (size_t)v*4);
    int hsel = lane >> 4;
    float dsel = hsel==0 ? edv.x : hsel==1 ? edv.y : hsel==2 ? edv.z : edv.w;
    float esel = hsel==0 ? esv.x : hsel==1 ? esv.y : hsel==2 ? esv.z : esv.w;
    float pself = __expf(lrelu(esel + dsel));          // self-loop, no max shift needed
    unsigned uself = hlinb[(size_t)v*64 + lane];
    float acc0 = pself * bf_lo(uself);
    float acc1 = pself * bf_hi(uself);
    float sum_p = pself;
    int beg = row_ptr[v], end = row_ptr[v+1];
    for (int base = beg; base < end; base += 64){
        int cnt = min(64, end - base);
        int sreg = 0;
        if (lane < cnt){
            sreg = col[base + lane];
            float4 q = *(const float4*)(es + (size_t)sreg*4);
            sp[w][0][lane] = __expf(lrelu(q.x + edv.x));
            sp[w][1][lane] = __expf(lrelu(q.y + edv.y));
            sp[w][2][lane] = __expf(lrelu(q.z + edv.z));
            sp[w][3][lane] = __expf(lrelu(q.w + edv.w));
        }
        asm volatile("s_waitcnt lgkmcnt(0)" ::: "memory");
        for (int jj = 0; jj < cnt; ++jj){
            int s = __builtin_amdgcn_readlane(sreg, jj);
            float p = sp[w][hsel][jj];
            unsigned u = hlinb[(size_t)s*64 + lane];
            sum_p += p;
            acc0 += p * bf_lo(u);
            acc1 += p * bf_hi(u);
        }
    }
    float inv = 1.f / (sum_p + 1e-16f);
    int c = lane * 2;
    float2 bb = *(const float2*)(b1 + c);
    float oA = eluf(acc0 * inv + bb.x);
    float oB = eluf(acc1 * inv + bb.y);
    float su = oA + oB;
    #pragma unroll
    for (int k = 32; k >= 1; k >>= 1) su += __shfl_xor(su, k);
    float mean = su * (1.f/128.f);
    float aA = oA - mean, aB = oB - mean;
    float vs = aA*aA + aB*aB;
    #pragma unroll
    for (int k = 32; k >= 1; k >>= 1) vs += __shfl_xor(vs, k);
    float rstd = rsqrtf(vs * (1.f/128.f) + LN_EPS);
    float2 gg = *(const float2*)(g1 + c);
    float2 ee = *(const float2*)(be1 + c);
    float2 r; r.x = aA*rstd*gg.x + ee.x; r.y = aB*rstd*gg.y + ee.y;
    *(float2*)(h1 + (size_t)v*128 + c) = r;
}

// ---------------- layer 2 linear: h1[N,128] @ W2[128,64] -> bf16 ----------------

__global__ __launch_bounds__(256) void k_lin2(
    const float* __restrict__ h1, const float* __restrict__ W2,
    const float* __restrict__ asrc, const float* __restrict__ adst,
    unsigned short* __restrict__ hlin2b, float* __restrict__ es2, float* __restrict__ ed2, int N)
{
    __shared__ float sW[128*64];
    __shared__ float sA[64], sB[64];
    int t = threadIdx.x;
    for (int i = t; i < 128*64; i += 256) sW[i] = W2[i];
    if (t < 64){ sA[t] = asrc[t]; sB[t] = adst[t]; }
    __syncthreads();
    int lane = t & 63;
    int v = blockIdx.x * 4 + (t >> 6);
    if (v >= N) return;
    const float* hv = h1 + (size_t)v*128;
    float acc = 0.f;
    #pragma unroll 8
    for (int k = 0; k < 128; k += 4){
        float4 h4 = *(const float4*)(hv + k);
        acc += h4.x * sW[(k  )*64 + lane];
        acc += h4.y * sW[(k+1)*64 + lane];
        acc += h4.z * sW[(k+2)*64 + lane];
        acc += h4.w * sW[(k+3)*64 + lane];
    }
    hlin2b[(size_t)v*64 + lane] = f2bf(acc);
    float ts = acc * sA[lane], td = acc * sB[lane];
    #pragma unroll
    for (int m = 16; m >= 1; m >>= 1){
        ts += __shfl_xor(ts, m); td += __shfl_xor(td, m);
    }
    if ((lane & 31) == 0){
        int h = lane >> 5;
        es2[(size_t)v*2 + h] = ts;
        ed2[(size_t)v*2 + h] = td;
    }
}

// ---------------- layer 2: fused single-pass attn+agg + head-mean + ELU + skip + LN ----------------

__global__ __launch_bounds__(256) void k_agg2(
    const unsigned short* __restrict__ hlin2b,   // [N][64] bf16
    const float* __restrict__ es2, const float* __restrict__ ed2,
    const int* __restrict__ row_ptr, const int* __restrict__ col,
    const float* __restrict__ x, const float* __restrict__ Wskip, const float* __restrict__ bskip,
    const float* __restrict__ b2, const float* __restrict__ g2, const float* __restrict__ be2,
    float* __restrict__ h2, int N)
{
    __shared__ float sp[4][2][68];
    int t = threadIdx.x, lane = t & 63, w = t >> 6;
    int v = blockIdx.x * 4 + w;
    if (v >= N) return;
    float2 edv = *(const float2*)(ed2 + (size_t)v*2);
    float2 esv = *(const float2*)(es2 + (size_t)v*2);
    int hsel = lane >> 5;
    float dsel = hsel ? edv.y : edv.x;
    float esel = hsel ? esv.y : esv.x;
    float pself = __expf(lrelu(esel + dsel));
    float acc = pself * __uint_as_float(((unsigned)hlin2b[(size_t)v*64 + lane]) << 16);
    float sum_p = pself;
    int beg = row_ptr[v], end = row_ptr[v+1];
    for (int base = beg; base < end; base += 64){
        int cnt = min(64, end - base);
        int sreg = 0;
        if (lane < cnt){
            sreg = col[base + lane];
            float2 q = *(const float2*)(es2 + (size_t)sreg*2);
            sp[w][0][lane] = __expf(lrelu(q.x + edv.x));
            sp[w][1][lane] = __expf(lrelu(q.y + edv.y));
        }
        asm volatile("s_waitcnt lgkmcnt(0)" ::: "memory");
        for (int jj = 0; jj < cnt; ++jj){
            int s = __builtin_amdgcn_readlane(sreg, jj);
            float p = sp[w][hsel][jj];
            unsigned short u = hlin2b[(size_t)s*64 + lane];
            sum_p += p;
            acc += p * __uint_as_float(((unsigned)u) << 16);
        }
    }
    acc /= (sum_p + 1e-16f);
    float other = __shfl(acc, lane ^ 32);
    if (lane < 32){
        float o = 0.5f * (acc + other) + b2[lane];
        o = eluf(o);
        float sk = x[(size_t)v*3]*Wskip[lane] + x[(size_t)v*3+1]*Wskip[32+lane]
                 + x[(size_t)v*3+2]*Wskip[64+lane] + bskip[lane];
        float z = o + sk;
        float su = z;
        #pragma unroll
        for (int k = 16; k >= 1; k >>= 1) su += __shfl_xor(su, k);
        float mean = su * (1.f/32.f);
        float d = z - mean;
        float vs = d*d;
        #pragma unroll
        for (int k = 16; k >= 1; k >>= 1) vs += __shfl_xor(vs, k);
        float rstd = rsqrtf(vs * (1.f/32.f) + LN_EPS);
        h2[(size_t)v*32 + lane] = d*rstd*g2[lane] + be2[lane];
    }
}

// ---------------- pooling: per-graph mean/max/std (batch sorted) + projection ----------------

__global__ __launch_bounds__(256) void k_pool(
    const float* __restrict__ h2, const int* __restrict__ batch,
    const float* __restrict__ Wp, const float* __restrict__ bp,
    float* __restrict__ out, int N)
{
    int g = blockIdx.x; int t = threadIdx.x;
    __shared__ int sBeg, sEnd;
    if (t == 0){
        int lo = 0, hi = N;
        while (lo < hi){ int mid = (lo+hi) >> 1; if (batch[mid] < g) lo = mid+1; else hi = mid; }
        sBeg = lo;
        lo = sBeg; hi = N;
        while (lo < hi){ int mid = (lo+hi) >> 1; if (batch[mid] < g+1) lo = mid+1; else hi = mid; }
        sEnd = lo;
    }
    __syncthreads();
    int beg = sBeg, end = sEnd;
    int ch = t & 31, grp = t >> 5;
    float sum = 0.f, sq = 0.f, mx = -INFINITY;
    for (int i = beg + grp; i < end; i += 8){
        float val = h2[(size_t)i*32 + ch];
        sum += val; sq += val*val; mx = fmaxf(mx, val);
    }
    __shared__ float lsum[256], lsq[256], lmx[256];
    lsum[t] = sum; lsq[t] = sq; lmx[t] = mx;
    __syncthreads();
    for (int s = 4; s >= 1; s >>= 1){
        if (grp < s){
            lsum[t] += lsum[t + s*32];
            lsq [t] += lsq [t + s*32];
            lmx [t]  = fmaxf(lmx[t], lmx[t + s*32]);
        }
        __syncthreads();
    }
    __shared__ float feat[96];
    if (t < 32){
        float cnt = fmaxf((float)(end - beg), 1.f);
        float mean = lsum[t] / cnt;
        float var  = lsq[t] / cnt - mean*mean;
        feat[t]      = mean;
        feat[32 + t] = lmx[t];
        feat[64 + t] = sqrtf(fmaxf(var, 0.f));
    }
    __syncthreads();
    if (t < 48){
        float acc = bp[t];
        #pragma unroll 8
        for (int k = 0; k < 96; ++k) acc += feat[k] * Wp[k*48 + t];
        out[(size_t)g*48 + t] = acc;
    }
}

// ---------------- launcher ----------------

extern "C" void kernel_launch(void* const* d_in, const int* in_sizes, int n_in,
                              void* d_out, int out_size, void* d_ws, size_t ws_size,
                              hipStream_t stream)
{
    const float* x     = (const float*)d_in[0];
    const int*   ei    = (const int*)  d_in[1];
    const int*   batch = (const int*)  d_in[2];
    const float* W1    = (const float*)d_in[3];
    const float* as1   = (const float*)d_in[4];
    const float* ad1   = (const float*)d_in[5];
    const float* b1    = (const float*)d_in[6];
    const float* W2    = (const float*)d_in[7];
    const float* as2   = (const float*)d_in[8];
    const float* ad2   = (const float*)d_in[9];
    const float* b2    = (const float*)d_in[10];
    const float* Wskip = (const float*)d_in[11];
    const float* bskip = (const float*)d_in[12];
    const float* g1    = (const float*)d_in[13];
    const float* be1   = (const float*)d_in[14];
    const float* g2    = (const float*)d_in[15];
    const float* be2   = (const float*)d_in[16];
    const float* Wp    = (const float*)d_in[17];
    const float* bp    = (const float*)d_in[18];

    int N = in_sizes[0] / 3;
    int E = in_sizes[1] / 2;
    int B = out_size / 48;
    const int* src = ei;
    const int* dst = ei + E;

    char* w = (char*)d_ws;
    auto alloc = [&](size_t bytes) -> char* {
        char* p = w; w += (bytes + 255) & ~(size_t)255; return p;
    };
    int*   row_ptr = (int*)  alloc((size_t)(N+1)*4);
    int*   deg     = (int*)  alloc((size_t)N*4);       // reused as fill cursor
    int*   partial = (int*)  alloc(4*1024);
    int*   col     = (int*)  alloc((size_t)E*4);
    unsigned* hlinb= (unsigned*)alloc((size_t)N*64*4); // layer1 bf16x2; layer2 reuses as u16[N][64]
    float* es      = (float*)alloc((size_t)N*4*4);     // layer2 reuses first N*2
    float* ed      = (float*)alloc((size_t)N*4*4);
    float* h1      = (float*)alloc((size_t)N*128*4);
    float* h2      = (float*)alloc((size_t)N*32*4);
    (void)ws_size;

    hipMemsetAsync(deg, 0, (size_t)N*4, stream);

    int eb  = (E + 255) / 256;
    int nch = (N + 255) / 256;
    int nb  = (N + 3) / 4;

    k_deg         <<<eb, 256, 0, stream>>>(dst, deg, E);
    k_chunk_sum   <<<nch, 256, 0, stream>>>(deg, partial, N);
    k_scan_partial<<<1, 512, 0, stream>>>(partial, nch);
    k_scan_final  <<<nch, 256, 0, stream>>>(deg, partial, row_ptr, deg, N);
    k_fill        <<<eb, 256, 0, stream>>>(src, dst, deg, col, E);

    k_lin1 <<<nb, 256, 0, stream>>>(x, W1, as1, ad1, hlinb, es, ed, N);
    k_agg1 <<<nb, 256, 0, stream>>>(hlinb, es, ed, row_ptr, col, b1, g1, be1, h1, N);
    k_lin2 <<<nb, 256, 0, stream>>>(h1, W2, as2, ad2, (unsigned short*)hlinb, es, ed, N);
    k_agg2 <<<nb, 256, 0, stream>>>((unsigned short*)hlinb, es, ed, row_ptr, col,
                                    x, Wskip, bskip, b2, g2, be2, h2, N);
    k_pool <<<B, 256, 0, stream>>>(h2, batch, Wp, bp, (float*)d_out, N);
}

// Round 3
// 491.850 us; speedup vs baseline: 1.6255x; 1.2310x over previous
//
#include <hip/hip_runtime.h>
#include <math.h>

#define NEG_SLOPE 0.2f
#define LN_EPS 1e-5f

typedef __attribute__((ext_vector_type(8))) short bf16x8;
typedef __attribute__((ext_vector_type(4))) float f32x4;

__device__ __forceinline__ float lrelu(float v){ return v > 0.f ? v : NEG_SLOPE * v; }
__device__ __forceinline__ float eluf (float v){ return v > 0.f ? v : expm1f(v); }

__device__ __forceinline__ unsigned short f2bf(float f){
    unsigned x = __float_as_uint(f);
    unsigned r = (x + 0x7fffu + ((x >> 16) & 1u)) >> 16;   // round-nearest-even
    return (unsigned short)r;
}
__device__ __forceinline__ float bf_lo(unsigned u){ return __uint_as_float(u << 16); }
__device__ __forceinline__ float bf_hi(unsigned u){ return __uint_as_float(u & 0xffff0000u); }

// ---------------- CSR build ----------------

__global__ void k_deg(const int* __restrict__ dst, int* __restrict__ deg, int E){
    int e = blockIdx.x * 256 + threadIdx.x;
    if (e < E) atomicAdd(&deg[dst[e]], 1);
}

__global__ void k_chunk_sum(const int* __restrict__ deg, int* __restrict__ partial, int N){
    __shared__ int lds[256];
    int t = threadIdx.x;
    int v = blockIdx.x * 256 + t;
    lds[t] = (v < N) ? deg[v] : 0;
    __syncthreads();
    for (int s = 128; s > 0; s >>= 1){
        if (t < s) lds[t] += lds[t + s];
        __syncthreads();
    }
    if (t == 0) partial[blockIdx.x] = lds[0];
}

__global__ void k_scan_partial(int* __restrict__ partial, int n){
    __shared__ int lds[512];
    int t = threadIdx.x;
    int x = (t < n) ? partial[t] : 0;
    lds[t] = x;
    __syncthreads();
    for (int s = 1; s < 512; s <<= 1){
        int a = (t >= s) ? lds[t - s] : 0;
        __syncthreads();
        lds[t] += a;
        __syncthreads();
    }
    if (t < n) partial[t] = lds[t] - x;   // exclusive
}

__global__ void k_scan_final(const int* __restrict__ deg, const int* __restrict__ partial,
                             int* __restrict__ row_ptr, int* __restrict__ cursor, int N){
    __shared__ int lds[256];
    int t = threadIdx.x;
    int v = blockIdx.x * 256 + t;
    int x = (v < N) ? deg[v] : 0;
    lds[t] = x;
    __syncthreads();
    for (int s = 1; s < 256; s <<= 1){
        int a = (t >= s) ? lds[t - s] : 0;
        __syncthreads();
        lds[t] += a;
        __syncthreads();
    }
    int rp = partial[blockIdx.x] + lds[t] - x;  // exclusive prefix
    if (v < N){
        row_ptr[v] = rp;
        cursor[v]  = rp;
        if (v == N - 1) row_ptr[N] = rp + x;
    }
}

__global__ void k_fill(const int* __restrict__ src, const int* __restrict__ dst,
                       int* __restrict__ cursor, int* __restrict__ col, int E){
    int e = blockIdx.x * 256 + threadIdx.x;
    if (e < E){
        int d = dst[e];
        int pos = atomicAdd(&cursor[d], 1);
        col[pos] = src[e];
    }
}

// ---------------- layer 1 linear: x[N,3] @ W1[3,128] -> bf16, e_src/e_dst ----------------

__global__ __launch_bounds__(256) void k_lin1(
    const float* __restrict__ x, const float* __restrict__ W1,
    const float* __restrict__ asrc, const float* __restrict__ adst,
    unsigned* __restrict__ hlinb, float* __restrict__ es, float* __restrict__ ed, int N)
{
    __shared__ float sW[384], sA[128], sB[128];
    int t = threadIdx.x;
    for (int i = t; i < 384; i += 256) sW[i] = W1[i];
    for (int i = t; i < 128; i += 256){ sA[i] = asrc[i]; sB[i] = adst[i]; }
    __syncthreads();
    int lane = t & 63;
    int v = blockIdx.x * 4 + (t >> 6);
    if (v >= N) return;
    float x0 = x[(size_t)v*3], x1 = x[(size_t)v*3+1], x2 = x[(size_t)v*3+2];
    int c = lane * 2;
    float h0 = x0*sW[c  ] + x1*sW[128+c  ] + x2*sW[256+c  ];
    float h1 = x0*sW[c+1] + x1*sW[128+c+1] + x2*sW[256+c+1];
    hlinb[(size_t)v*64 + lane] = (unsigned)f2bf(h0) | ((unsigned)f2bf(h1) << 16);
    int hsel = lane >> 4;
    float ts = h0*sA[c] + h1*sA[c+1];
    float td = h0*sB[c] + h1*sB[c+1];
    #pragma unroll
    for (int m = 8; m >= 1; m >>= 1){
        ts += __shfl_xor(ts, m); td += __shfl_xor(td, m);
    }
    if ((lane & 15) == 0){
        es[(size_t)v*4 + hsel] = ts;
        ed[(size_t)v*4 + hsel] = td;
    }
}

// ---------------- layer 1: fused single-pass attention + agg + bias + ELU + LN -> bf16 ----------------

__global__ __launch_bounds__(256) void k_agg1(
    const unsigned* __restrict__ hlinb,     // [N][64] bf16x2
    const float* __restrict__ es, const float* __restrict__ ed,
    const int* __restrict__ row_ptr, const int* __restrict__ col,
    const float* __restrict__ b1, const float* __restrict__ g1, const float* __restrict__ be1,
    unsigned* __restrict__ h1b, int N)
{
    __shared__ float sp[4][4][68];   // [wave][head][edge], padded
    int t = threadIdx.x, lane = t & 63, w = t >> 6;
    int v = blockIdx.x * 4 + w;
    if (v >= N) return;
    float4 edv = *(const float4*)(ed + (size_t)v*4);
    float4 esv = *(const float4*)(es + (size_t)v*4);
    int hsel = lane >> 4;
    float dsel = hsel==0 ? edv.x : hsel==1 ? edv.y : hsel==2 ? edv.z : edv.w;
    float esel = hsel==0 ? esv.x : hsel==1 ? esv.y : hsel==2 ? esv.z : esv.w;
    float pself = __expf(lrelu(esel + dsel));          // no max-shift: logits are O(1)
    unsigned uself = hlinb[(size_t)v*64 + lane];
    float acc0 = pself * bf_lo(uself);
    float acc1 = pself * bf_hi(uself);
    float sum_p = pself;
    int beg = row_ptr[v], end = row_ptr[v+1];
    for (int base = beg; base < end; base += 64){
        int cnt = min(64, end - base);
        int sreg = 0;
        if (lane < cnt){
            sreg = col[base + lane];
            float4 q = *(const float4*)(es + (size_t)sreg*4);
            sp[w][0][lane] = __expf(lrelu(q.x + edv.x));
            sp[w][1][lane] = __expf(lrelu(q.y + edv.y));
            sp[w][2][lane] = __expf(lrelu(q.z + edv.z));
            sp[w][3][lane] = __expf(lrelu(q.w + edv.w));
        }
        asm volatile("s_waitcnt lgkmcnt(0)" ::: "memory");
        for (int jj = 0; jj < cnt; ++jj){
            int s = __builtin_amdgcn_readlane(sreg, jj);
            float p = sp[w][hsel][jj];
            unsigned u = hlinb[(size_t)s*64 + lane];
            sum_p += p;
            acc0 += p * bf_lo(u);
            acc1 += p * bf_hi(u);
        }
    }
    float inv = 1.f / (sum_p + 1e-16f);
    int c = lane * 2;
    float2 bb = *(const float2*)(b1 + c);
    float oA = eluf(acc0 * inv + bb.x);
    float oB = eluf(acc1 * inv + bb.y);
    float su = oA + oB;
    #pragma unroll
    for (int k = 32; k >= 1; k >>= 1) su += __shfl_xor(su, k);
    float mean = su * (1.f/128.f);
    float aA = oA - mean, aB = oB - mean;
    float vs = aA*aA + aB*aB;
    #pragma unroll
    for (int k = 32; k >= 1; k >>= 1) vs += __shfl_xor(vs, k);
    float rstd = rsqrtf(vs * (1.f/128.f) + LN_EPS);
    float2 gg = *(const float2*)(g1 + c);
    float2 ee = *(const float2*)(be1 + c);
    float rx = aA*rstd*gg.x + ee.x, ry = aB*rstd*gg.y + ee.y;
    h1b[(size_t)v*64 + lane] = (unsigned)f2bf(rx) | ((unsigned)f2bf(ry) << 16);
}

// ---------------- layer 2 linear via MFMA: h1b[N,128]bf16 @ W2[128,64] ----------------
// block = 4 waves, 64 nodes; wave w: rows vb..vb+15, all 64 cols.
// A frag: row=lane&15, k=(lane>>4)*8+j ; C/D: col=lane&15, row=(lane>>4)*4+reg

__global__ __launch_bounds__(256) void k_lin2(
    const unsigned short* __restrict__ h1b,   // [N][128] bf16
    const float* __restrict__ W2,             // [128][64] fp32
    const float* __restrict__ asrc, const float* __restrict__ adst,
    unsigned short* __restrict__ hlin2b, float* __restrict__ es2, float* __restrict__ ed2, int N)
{
    int t = threadIdx.x, lane = t & 63, w = t >> 6;
    int vb = blockIdx.x * 64 + w * 16;
    if (vb >= N) return;
    int lo4 = lane & 15, hi4 = lane >> 4;

    int arow = vb + lo4; if (arow >= N) arow = N - 1;
    const unsigned short* ap = h1b + (size_t)arow*128 + hi4*8;
    bf16x8 a0 = *(const bf16x8*)(ap);
    bf16x8 a1 = *(const bf16x8*)(ap + 32);
    bf16x8 a2 = *(const bf16x8*)(ap + 64);
    bf16x8 a3 = *(const bf16x8*)(ap + 96);

    f32x4 acc[4];
    #pragma unroll
    for (int nt = 0; nt < 4; ++nt) acc[nt] = (f32x4){0.f, 0.f, 0.f, 0.f};

    #pragma unroll
    for (int nt = 0; nt < 4; ++nt){
        int cb = nt*16 + lo4;
        #pragma unroll
        for (int kt = 0; kt < 4; ++kt){
            const float* wp = W2 + (size_t)(kt*32 + hi4*8)*64 + cb;
            bf16x8 b;
            #pragma unroll
            for (int j = 0; j < 8; ++j) b[j] = (short)f2bf(wp[(size_t)j*64]);
            bf16x8 a = (kt==0) ? a0 : (kt==1) ? a1 : (kt==2) ? a2 : a3;
            acc[nt] = __builtin_amdgcn_mfma_f32_16x16x32_bf16(a, b, acc[nt], 0, 0, 0);
        }
    }

    float sa0 = asrc[lo4], sa1 = asrc[16+lo4], sa2 = asrc[32+lo4], sa3 = asrc[48+lo4];
    float sb0 = adst[lo4], sb1 = adst[16+lo4], sb2 = adst[32+lo4], sb3 = adst[48+lo4];

    #pragma unroll
    for (int reg = 0; reg < 4; ++reg){
        int nr = vb + hi4*4 + reg;
        bool ok = nr < N;
        float c0 = acc[0][reg], c1 = acc[1][reg], c2 = acc[2][reg], c3 = acc[3][reg];
        if (ok){
            unsigned short* hp = hlin2b + (size_t)nr*64 + lo4;
            hp[ 0] = f2bf(c0);
            hp[16] = f2bf(c1);
            hp[32] = f2bf(c2);
            hp[48] = f2bf(c3);
        }
        float ps0 = c0*sa0 + c1*sa1, ps1 = c2*sa2 + c3*sa3;
        float pd0 = c0*sb0 + c1*sb1, pd1 = c2*sb2 + c3*sb3;
        #pragma unroll
        for (int m = 8; m >= 1; m >>= 1){
            ps0 += __shfl_xor(ps0, m); ps1 += __shfl_xor(ps1, m);
            pd0 += __shfl_xor(pd0, m); pd1 += __shfl_xor(pd1, m);
        }
        if (ok && lo4 == 0){
            float2 e; e.x = ps0; e.y = ps1;
            float2 d; d.x = pd0; d.y = pd1;
            *(float2*)(es2 + (size_t)nr*2) = e;
            *(float2*)(ed2 + (size_t)nr*2) = d;
        }
    }
}

// ---------------- layer 2: fused single-pass attn+agg + head-mean + ELU + skip + LN ----------------

__global__ __launch_bounds__(256) void k_agg2(
    const unsigned short* __restrict__ hlin2b,   // [N][64] bf16
    const float* __restrict__ es2, const float* __restrict__ ed2,
    const int* __restrict__ row_ptr, const int* __restrict__ col,
    const float* __restrict__ x, const float* __restrict__ Wskip, const float* __restrict__ bskip,
    const float* __restrict__ b2, const float* __restrict__ g2, const float* __restrict__ be2,
    float* __restrict__ h2, int N)
{
    __shared__ float sp[4][2][68];
    int t = threadIdx.x, lane = t & 63, w = t >> 6;
    int v = blockIdx.x * 4 + w;
    if (v >= N) return;
    float2 edv = *(const float2*)(ed2 + (size_t)v*2);
    float2 esv = *(const float2*)(es2 + (size_t)v*2);
    int hsel = lane >> 5;
    float dsel = hsel ? edv.y : edv.x;
    float esel = hsel ? esv.y : esv.x;
    float pself = __expf(lrelu(esel + dsel));
    float acc = pself * __uint_as_float(((unsigned)hlin2b[(size_t)v*64 + lane]) << 16);
    float sum_p = pself;
    int beg = row_ptr[v], end = row_ptr[v+1];
    for (int base = beg; base < end; base += 64){
        int cnt = min(64, end - base);
        int sreg = 0;
        if (lane < cnt){
            sreg = col[base + lane];
            float2 q = *(const float2*)(es2 + (size_t)sreg*2);
            sp[w][0][lane] = __expf(lrelu(q.x + edv.x));
            sp[w][1][lane] = __expf(lrelu(q.y + edv.y));
        }
        asm volatile("s_waitcnt lgkmcnt(0)" ::: "memory");
        for (int jj = 0; jj < cnt; ++jj){
            int s = __builtin_amdgcn_readlane(sreg, jj);
            float p = sp[w][hsel][jj];
            unsigned short u = hlin2b[(size_t)s*64 + lane];
            sum_p += p;
            acc += p * __uint_as_float(((unsigned)u) << 16);
        }
    }
    acc /= (sum_p + 1e-16f);
    float other = __shfl(acc, lane ^ 32);
    if (lane < 32){
        float o = 0.5f * (acc + other) + b2[lane];
        o = eluf(o);
        float sk = x[(size_t)v*3]*Wskip[lane] + x[(size_t)v*3+1]*Wskip[32+lane]
                 + x[(size_t)v*3+2]*Wskip[64+lane] + bskip[lane];
        float z = o + sk;
        float su = z;
        #pragma unroll
        for (int k = 16; k >= 1; k >>= 1) su += __shfl_xor(su, k);
        float mean = su * (1.f/32.f);
        float d = z - mean;
        float vs = d*d;
        #pragma unroll
        for (int k = 16; k >= 1; k >>= 1) vs += __shfl_xor(vs, k);
        float rstd = rsqrtf(vs * (1.f/32.f) + LN_EPS);
        h2[(size_t)v*32 + lane] = d*rstd*g2[lane] + be2[lane];
    }
}

// ---------------- pooling: per-graph mean/max/std (batch sorted) + projection ----------------

__global__ __launch_bounds__(256) void k_pool(
    const float* __restrict__ h2, const int* __restrict__ batch,
    const float* __restrict__ Wp, const float* __restrict__ bp,
    float* __restrict__ out, int N)
{
    int g = blockIdx.x; int t = threadIdx.x;
    __shared__ int sBeg, sEnd;
    if (t == 0){
        int lo = 0, hi = N;
        while (lo < hi){ int mid = (lo+hi) >> 1; if (batch[mid] < g) lo = mid+1; else hi = mid; }
        sBeg = lo;
        lo = sBeg; hi = N;
        while (lo < hi){ int mid = (lo+hi) >> 1; if (batch[mid] < g+1) lo = mid+1; else hi = mid; }
        sEnd = lo;
    }
    __syncthreads();
    int beg = sBeg, end = sEnd;
    int ch = t & 31, grp = t >> 5;
    float sum = 0.f, sq = 0.f, mx = -INFINITY;
    for (int i = beg + grp; i < end; i += 8){
        float val = h2[(size_t)i*32 + ch];
        sum += val; sq += val*val; mx = fmaxf(mx, val);
    }
    __shared__ float lsum[256], lsq[256], lmx[256];
    lsum[t] = sum; lsq[t] = sq; lmx[t] = mx;
    __syncthreads();
    for (int s = 4; s >= 1; s >>= 1){
        if (grp < s){
            lsum[t] += lsum[t + s*32];
            lsq [t] += lsq [t + s*32];
            lmx [t]  = fmaxf(lmx[t], lmx[t + s*32]);
        }
        __syncthreads();
    }
    __shared__ float feat[96];
    if (t < 32){
        float cnt = fmaxf((float)(end - beg), 1.f);
        float mean = lsum[t] / cnt;
        float var  = lsq[t] / cnt - mean*mean;
        feat[t]      = mean;
        feat[32 + t] = lmx[t];
        feat[64 + t] = sqrtf(fmaxf(var, 0.f));
    }
    __syncthreads();
    if (t < 48){
        float acc = bp[t];
        #pragma unroll 8
        for (int k = 0; k < 96; ++k) acc += feat[k] * Wp[k*48 + t];
        out[(size_t)g*48 + t] = acc;
    }
}

// ---------------- launcher ----------------

extern "C" void kernel_launch(void* const* d_in, const int* in_sizes, int n_in,
                              void* d_out, int out_size, void* d_ws, size_t ws_size,
                              hipStream_t stream)
{
    const float* x     = (const float*)d_in[0];
    const int*   ei    = (const int*)  d_in[1];
    const int*   batch = (const int*)  d_in[2];
    const float* W1    = (const float*)d_in[3];
    const float* as1   = (const float*)d_in[4];
    const float* ad1   = (const float*)d_in[5];
    const float* b1    = (const float*)d_in[6];
    const float* W2    = (const float*)d_in[7];
    const float* as2   = (const float*)d_in[8];
    const float* ad2   = (const float*)d_in[9];
    const float* b2    = (const float*)d_in[10];
    const float* Wskip = (const float*)d_in[11];
    const float* bskip = (const float*)d_in[12];
    const float* g1    = (const float*)d_in[13];
    const float* be1   = (const float*)d_in[14];
    const float* g2    = (const float*)d_in[15];
    const float* be2   = (const float*)d_in[16];
    const float* Wp    = (const float*)d_in[17];
    const float* bp    = (const float*)d_in[18];

    int N = in_sizes[0] / 3;
    int E = in_sizes[1] / 2;
    int B = out_size / 48;
    const int* src = ei;
    const int* dst = ei + E;

    char* w = (char*)d_ws;
    auto alloc = [&](size_t bytes) -> char* {
        char* p = w; w += (bytes + 255) & ~(size_t)255; return p;
    };
    int*   row_ptr = (int*)  alloc((size_t)(N+1)*4);
    int*   deg     = (int*)  alloc((size_t)N*4);       // reused as fill cursor
    int*   partial = (int*)  alloc(4*1024);
    int*   col     = (int*)  alloc((size_t)E*4);
    unsigned* hlinb= (unsigned*)alloc((size_t)N*64*4); // L1: bf16x2[N][64]; L2 reuses as u16[N][64]
    float* es      = (float*)alloc((size_t)N*4*4);     // layer2 reuses first N*2
    float* ed      = (float*)alloc((size_t)N*4*4);
    unsigned* h1b  = (unsigned*)alloc((size_t)N*64*4); // bf16x2[N][64] == bf16[N][128]
    float* h2      = (float*)alloc((size_t)N*32*4);
    (void)ws_size;

    hipMemsetAsync(deg, 0, (size_t)N*4, stream);

    int eb  = (E + 255) / 256;
    int nch = (N + 255) / 256;
    int nb  = (N + 3) / 4;
    int nb2 = (N + 63) / 64;

    k_deg         <<<eb, 256, 0, stream>>>(dst, deg, E);
    k_chunk_sum   <<<nch, 256, 0, stream>>>(deg, partial, N);
    k_scan_partial<<<1, 512, 0, stream>>>(partial, nch);
    k_scan_final  <<<nch, 256, 0, stream>>>(deg, partial, row_ptr, deg, N);
    k_fill        <<<eb, 256, 0, stream>>>(src, dst, deg, col, E);

    k_lin1 <<<nb, 256, 0, stream>>>(x, W1, as1, ad1, hlinb, es, ed, N);
    k_agg1 <<<nb, 256, 0, stream>>>(hlinb, es, ed, row_ptr, col, b1, g1, be1, h1b, N);
    k_lin2 <<<nb2, 256, 0, stream>>>((const unsigned short*)h1b, W2, as2, ad2,
                                     (unsigned short*)hlinb, es, ed, N);
    k_agg2 <<<nb, 256, 0, stream>>>((unsigned short*)hlinb, es, ed, row_ptr, col,
                                    x, Wskip, bskip, b2, g2, be2, h2, N);
    k_pool <<<B, 256, 0, stream>>>(h2, batch, Wp, bp, (float*)d_out, N);
}